// Round 6
// baseline (1177.272 us; speedup 1.0000x reference)
//
#include <hip/hip_runtime.h>
#include <hip/hip_bf16.h>
#include <hip/hip_fp8.h>
#include <math.h>

#define Nn 20000
#define Ee 320000
#define Dd 512
#define Hh 4
#define Cc 256
#define Ll 4
#define Bb 16
#define HC 1024               // H*C
#define ETOT (Ee + Nn)        // edges + self loops = 340000
#define NEG_SLOPE 0.2f
#define LN_EPS 1e-5f
#define NBLK ((Nn + 255) / 256)   // 79 scan blocks

typedef __attribute__((ext_vector_type(8))) __bf16 bf16x8;
typedef __attribute__((ext_vector_type(4))) __bf16 bf16x4;
typedef __attribute__((ext_vector_type(4))) float f32x4;
typedef __attribute__((ext_vector_type(2))) float f32x2;

// fp8 e4m3 (OCP) x4 decode — HW packed cvt if available
__device__ __forceinline__ f32x4 fp8x4_to_f32(unsigned int v) {
#if __has_builtin(__builtin_amdgcn_cvt_pk_f32_fp8)
    f32x2 lo = __builtin_amdgcn_cvt_pk_f32_fp8((int)v, false);
    f32x2 hi = __builtin_amdgcn_cvt_pk_f32_fp8((int)v, true);
    f32x4 r; r[0] = lo[0]; r[1] = lo[1]; r[2] = hi[0]; r[3] = hi[1];
    return r;
#else
    f32x4 r;
    #pragma unroll
    for (int i = 0; i < 4; ++i) {
        __hip_fp8_e4m3 q; q.__x = (v >> (8 * i)) & 0xff;
        r[i] = (float)q;
    }
    return r;
#endif
}

__device__ __forceinline__ unsigned char f32_to_fp8(float f) {
    return __hip_fp8_e4m3(f).__x;
}

// ---------------- CSR build ----------------

__device__ __forceinline__ void decode_edge(const int* ei, int e, int& s, int& d) {
    if (e < Ee) { s = ei[e]; d = ei[Ee + e]; }
    else        { s = e - Ee; d = e - Ee; }   // self loop
}

__global__ void count_deg_kernel(const int* __restrict__ ei, int* __restrict__ deg) {
    int e = blockIdx.x * blockDim.x + threadIdx.x;
    if (e >= ETOT) return;
    int s, d; decode_edge(ei, e, s, d);
    atomicAdd(&deg[d], 1);
}

__global__ void scan1_kernel(const int* __restrict__ deg, int* __restrict__ tmp,
                             int* __restrict__ bsum) {
    __shared__ int sd[256];
    int tid = threadIdx.x;
    int i = blockIdx.x * 256 + tid;
    sd[tid] = (i < Nn) ? deg[i] : 0;
    __syncthreads();
    for (int off = 1; off < 256; off <<= 1) {
        int t = (tid >= off) ? sd[tid - off] : 0;
        __syncthreads();
        sd[tid] += t;
        __syncthreads();
    }
    if (i < Nn) tmp[i] = sd[tid];
    if (tid == 255) bsum[blockIdx.x] = sd[255];
}

__global__ void scan2_kernel(int* __restrict__ bsum) {   // single block, NBLK<=256
    __shared__ int sd[256];
    int tid = threadIdx.x;
    sd[tid] = (tid < NBLK) ? bsum[tid] : 0;
    __syncthreads();
    for (int off = 1; off < 256; off <<= 1) {
        int t = (tid >= off) ? sd[tid - off] : 0;
        __syncthreads();
        sd[tid] += t;
        __syncthreads();
    }
    if (tid < NBLK) bsum[tid] = sd[tid];
}

__global__ void scan3_kernel(const int* __restrict__ tmp, const int* __restrict__ bsum,
                             const int* __restrict__ deg,
                             int* __restrict__ row_ptr, int* __restrict__ cursor) {
    int i = blockIdx.x * 256 + threadIdx.x;
    if (i >= Nn) return;
    int boff = (blockIdx.x == 0) ? 0 : bsum[blockIdx.x - 1];
    int incl = tmp[i] + boff;
    row_ptr[i + 1] = incl;
    cursor[i] = incl - deg[i];
    if (i == 0) row_ptr[0] = 0;
}

__global__ void scatter_kernel(const int* __restrict__ ei, int* __restrict__ cursor,
                               int* __restrict__ csr_src) {
    int e = blockIdx.x * blockDim.x + threadIdx.x;
    if (e >= ETOT) return;
    int s, d; decode_edge(ei, e, s, d);
    int pos = atomicAdd(&cursor[d], 1);
    csr_src[pos] = s;
}

// ---------------- casts ----------------

__global__ void cast_kernel(const float* __restrict__ in, __bf16* __restrict__ out, int n4) {
    int i = blockIdx.x * blockDim.x + threadIdx.x;
    if (i >= n4) return;
    f32x4 v = ((const f32x4*)in)[i];
    bf16x4 o;
    #pragma unroll
    for (int k = 0; k < 4; ++k) o[k] = (__bf16)v[k];
    ((bf16x4*)out)[i] = o;
}

// W[K][N] fp32 -> WT[N][K] bf16; grid.z selects matrix (stride K*N)
__global__ void transpose_cast_kernel(const float* __restrict__ W, __bf16* __restrict__ WT,
                                      int K, int N) {
    __shared__ float tile[32][33];
    W  += (size_t)blockIdx.z * K * N;
    WT += (size_t)blockIdx.z * K * N;
    int n0 = blockIdx.x * 32, k0 = blockIdx.y * 32;
    for (int i = threadIdx.y; i < 32; i += 8)
        tile[i][threadIdx.x] = W[(size_t)(k0 + i) * N + n0 + threadIdx.x];
    __syncthreads();
    for (int i = threadIdx.y; i < 32; i += 8)
        WT[(size_t)(n0 + i) * K + k0 + threadIdx.x] = (__bf16)tile[threadIdx.x][i];
}

// ---------------- MFMA GEMM + fused alpha epilogue (r0 VERBATIM — proven 65us) ----------
// C8[M,1024](fp8) = A[M,K](bf16) @ BT[1024,K]^T. XCD swizzle (r11: FETCH 162->34MB).
// r18 note: r15/r16/r17 all tried intra-block pipelining (counted vmcnt, deep
// buffers, issue-early dbuf) and ALL regressed (98/83/77us vs 65us): every scheme
// grew LDS and traded away co-resident blocks; inter-block overlap (m114) beats
// intra-block pipelining here. This 32KB-LDS stage->sync->compute->sync structure
// at 2+ blocks/CU is the empirical local optimum — do not touch without new
// counter evidence. (r18 bench re-confirmed: 66us, MfmaUtil 25-26%, FETCH 34.8MB.)
// Epilogue computes alpha partials ps/pd from IN-REGISTER h (zero extra traffic).
// Race-free: part=(cblk&1)*2+(wave&1) — for fixed (row,head) the 4 writers
// (cblk in {2h,2h+1} x wave&1) get distinct parts. No atomics, no pre-zeroing.

__device__ __forceinline__ void async16(const __bf16* g, __bf16* l) {
    __builtin_amdgcn_global_load_lds((const __attribute__((address_space(1))) void*)g,
                                     (__attribute__((address_space(3))) void*)l,
                                     16, 0, 0);
}

__global__ __launch_bounds__(256) void mfma_gemm_kernel(
    const __bf16* __restrict__ A,   // [M][K]
    const __bf16* __restrict__ BT,  // [1024][K]
    unsigned char* __restrict__ C8, // [M][1024] fp8 e4m3 (agg gather payload)
    const float* __restrict__ att_s,  // [4][256] this layer
    const float* __restrict__ att_d,  // [4][256]
    float* __restrict__ aprt_s,     // [4][M][4] partials (race-free)
    float* __restrict__ aprt_d,     // [4][M][4]
    int M, int K)
{
    int lin = blockIdx.y * 8 + blockIdx.x;          // grid (8, 160) -> 1280 ids
    int rblk = (lin >> 6) * 8 + (lin & 7);
    int cblk = (lin >> 3) & 7;
    int rowBase = rblk * 128, colBase = cblk * 128;
    if (rowBase >= M) return;

    __shared__ __bf16 As[2][128 * 32];
    __shared__ __bf16 Bs[2][128 * 32];
    int tid = threadIdx.x;
    int wave = tid >> 6, lane = tid & 63;
    int m16 = lane & 15, quad = lane >> 4;
    int waveRow = (wave >> 1) * 64, waveCol = (wave & 1) * 64;

    f32x4 acc[4][4] = {};

    int srow = wave * 32 + (lane >> 2);          // staging row, +16 for second half
    int gch0 = (lane & 3) ^ ((srow >> 1) & 3);
    int gch1 = (lane & 3) ^ (((srow + 16) >> 1) & 3);
    int gr0 = rowBase + srow;       if (gr0 >= M) gr0 = M - 1;
    int gr1 = rowBase + srow + 16;  if (gr1 >= M) gr1 = M - 1;
    int ldsOff = srow * 32 + (lane & 3) * 8;

    for (int k0 = 0; k0 < K; k0 += 64) {
        #pragma unroll
        for (int p = 0; p < 2; ++p) {
            int kp = k0 + p * 32;
            async16(A + (size_t)gr0 * K + kp + gch0 * 8, &As[p][ldsOff]);
            async16(A + (size_t)gr1 * K + kp + gch1 * 8, &As[p][ldsOff + 16 * 32]);
            async16(BT + (size_t)(colBase + srow) * K + kp + gch0 * 8, &Bs[p][ldsOff]);
            async16(BT + (size_t)(colBase + srow + 16) * K + kp + gch1 * 8, &Bs[p][ldsOff + 16 * 32]);
        }
        __syncthreads();
        #pragma unroll
        for (int p = 0; p < 2; ++p) {
            bf16x8 af[4], bfr[4];
            #pragma unroll
            for (int i = 0; i < 4; ++i) {
                int row = waveRow + i * 16 + m16;
                af[i] = *(const bf16x8*)&As[p][row * 32 + (quad ^ ((row >> 1) & 3)) * 8];
                int col = waveCol + i * 16 + m16;
                bfr[i] = *(const bf16x8*)&Bs[p][col * 32 + (quad ^ ((col >> 1) & 3)) * 8];
            }
            #pragma unroll
            for (int i = 0; i < 4; ++i)
                #pragma unroll
                for (int j = 0; j < 4; ++j)
                    acc[i][j] = __builtin_amdgcn_mfma_f32_16x16x32_bf16(af[i], bfr[j], acc[i][j], 0, 0, 0);
        }
        __syncthreads();
    }

    // att weights for this wave's 64-col span (single head: span never crosses 256)
    int cbase = colBase + waveCol;
    int head = cbase >> 8;
    int part = (cblk & 1) * 2 + (wave & 1);
    float as4[4], ad4[4];
    #pragma unroll
    for (int j = 0; j < 4; ++j) {
        int off = (cbase + j * 16 + m16) & 255;
        as4[j] = att_s[head * 256 + off];
        ad4[j] = att_d[head * 256 + off];
    }

    // fp8 stores (C/D layout: col=lane&15, row=quad*4+reg) + alpha partials
    #pragma unroll
    for (int i = 0; i < 4; ++i) {
        int r0 = rowBase + waveRow + i * 16 + quad * 4;
        #pragma unroll
        for (int r = 0; r < 4; ++r) {
            int row = r0 + r;
            float ps = 0.f, pd = 0.f;
            #pragma unroll
            for (int j = 0; j < 4; ++j) {
                float h = acc[i][j][r];
                ps += h * as4[j];
                pd += h * ad4[j];
                if (row < M)
                    C8[(size_t)row * HC + colBase + waveCol + j * 16 + m16] = f32_to_fp8(h);
            }
            #pragma unroll
            for (int off = 1; off < 16; off <<= 1) {
                ps += __shfl_xor(ps, off);
                pd += __shfl_xor(pd, off);
            }
            if (m16 == 0 && row < M) {
                aprt_s[((size_t)part * M + row) * 4 + head] = ps;
                aprt_d[((size_t)part * M + row) * 4 + head] = pd;
            }
        }
    }
}

// ---------------- alpha partial reduce: asrc/adst[n] = sum over 4 parts ----------------

__global__ void alpha_sum_kernel(const float* __restrict__ aprt_s,
                                 const float* __restrict__ aprt_d,
                                 float* __restrict__ asrc, float* __restrict__ adst) {
    int n = blockIdx.x * 256 + threadIdx.x;
    if (n >= Nn) return;
    f32x4 s = {0.f, 0.f, 0.f, 0.f}, d = {0.f, 0.f, 0.f, 0.f};
    #pragma unroll
    for (int p = 0; p < 4; ++p) {
        f32x4 vs = ((const f32x4*)aprt_s)[(size_t)p * Nn + n];
        f32x4 vd = ((const f32x4*)aprt_d)[(size_t)p * Nn + n];
        #pragma unroll
        for (int k = 0; k < 4; ++k) { s[k] += vs[k]; d[k] += vd[k]; }
    }
    ((f32x4*)asrc)[n] = s;
    ((f32x4*)adst)[n] = d;
}

// ---------------- edge-weight precompute (head-major output) ----------------
// r19: 16 lanes/node (avg degree 17 -> ~70% lane util, ~10000 wave-bodies).

__global__ __launch_bounds__(256) void ew_kernel(const float* __restrict__ asrc,
                                                 const float* __restrict__ adst,
                                                 const int* __restrict__ row_ptr,
                                                 const int* __restrict__ csr_src,
                                                 float* __restrict__ ewT,
                                                 float* __restrict__ dinv) {
    int grp = threadIdx.x >> 4, lane16 = threadIdx.x & 15;
    int n = blockIdx.x * 16 + grp;
    if (n >= Nn) return;
    int start = row_ptr[n], end = row_ptr[n + 1];
    f32x4 ad = ((const f32x4*)adst)[n];
    f32x4 d = {0.f, 0.f, 0.f, 0.f};
    for (int e = start + lane16; e < end; e += 16) {
        int s = csr_src[e];
        f32x4 as = ((const f32x4*)asrc)[s];
        #pragma unroll
        for (int k = 0; k < 4; ++k) {
            float z = as[k] + ad[k];
            z = (z > 0.f) ? z : NEG_SLOPE * z;
            float ex = __expf(z);
            ewT[(size_t)k * ETOT + e] = ex;
            d[k] += ex;
        }
    }
    #pragma unroll
    for (int off = 8; off > 0; off >>= 1) {
        #pragma unroll
        for (int k = 0; k < 4; ++k) d[k] += __shfl_xor(d[k], off);
    }
    if (lane16 == 0) {
        f32x4 iv;
        #pragma unroll
        for (int k = 0; k < 4; ++k) iv[k] = 1.f / (d[k] + 1e-16f);
        ((f32x4*)dinv)[n] = iv;
    }
}

// ---------------- sliced aggregation — r20: edge-balanced walk + LDS accumulators -------
// Previous structure (8-lane group serially walks ITS node's edges) was straggler-
// bound: wave time = max degree over 8 resident nodes (~26 vs mean 17 => ~65% util),
// which explains r18 (4-wide ILP) and r19 (fewer lane-ops) both under-delivering.
// Now each 8-lane group owns a FIXED contiguous 32-edge window (perfect balance);
// equal-dst runs (avg 17, CSR dst-sorted) accumulate in 16 regs and flush to a
// per-block LDS f32 tile (32 nodes x 128ch, +4 pad) via ds_add_f32 on dst change
// (~3 flushes / 32-edge window). dst-local via 5-step binary search at staging,
// packed into bits 20-24 of the src word. Reduction-order change only (~1e-6 rel).
// LDS ~25KB -> ~6 blocks/CU. grid (8, 625): slice -> XCD affinity kept (r10).

__global__ __launch_bounds__(256) void agg_slice_kernel(
    const unsigned char* __restrict__ h8,
    const float* __restrict__ ewT,
    const float* __restrict__ dinv,
    const int* __restrict__ row_ptr,
    const int* __restrict__ csr_src,
    const float* __restrict__ bias_l,
    __bf16* __restrict__ outb)
{
    int slice = blockIdx.x;              // 0..7
    int head = slice >> 1;
    int tid = threadIdx.x;
    int slot = tid >> 3;                 // 0..31 edge-window slot
    int ch = tid & 7;                    // 16B fp8 group within 128B slice

    __shared__ int2  ce_sh[1024];        // (src | dstloc<<20, bitcast w)
    __shared__ float acc_sh[32 * 132];   // 32 nodes x 128 f32 (+4 pad vs bank aliasing)
    __shared__ int   rp_sh[33];

    if (tid < 33) rp_sh[tid] = row_ptr[blockIdx.y * 32 + tid];
    for (int i = tid; i < 32 * 132; i += 256) acc_sh[i] = 0.f;
    __syncthreads();
    int blk_lo = rp_sh[0], blk_hi = rp_sh[32];

    const unsigned char* hs = h8 + slice * 128 + ch * 16;
    const float* ewh = ewT + (size_t)head * ETOT;

    for (int c0 = blk_lo; c0 < blk_hi; c0 += 1024) {
        int c1 = min(c0 + 1024, blk_hi);
        int cnt = c1 - c0;
        for (int i = tid; i < cnt; i += 256) {     // coalesced stage + dstloc search
            int eg = c0 + i;
            int lo = 0, hi = 32;
            while (hi - lo > 1) { int mid = (lo + hi) >> 1; if (rp_sh[mid] <= eg) lo = mid; else hi = mid; }
            int2 v;
            v.x = csr_src[eg] | (lo << 20);
            v.y = __float_as_int(ewh[eg]);
            ce_sh[i] = v;
        }
        __syncthreads();
        int e0 = c0 + slot * 32;
        int e1 = min(e0 + 32, c1);
        float racc[16];
        #pragma unroll
        for (int k = 0; k < 16; ++k) racc[k] = 0.f;
        int curd = -1;
        for (int e = e0; e < e1; ++e) {
            int2 v = ce_sh[e - c0];
            int d = v.x >> 20;
            if (d != curd) {
                if (curd >= 0) {
                    float* ap = &acc_sh[curd * 132 + ch * 16];
                    #pragma unroll
                    for (int k = 0; k < 16; ++k) { atomicAdd(&ap[k], racc[k]); racc[k] = 0.f; }
                }
                curd = d;
            }
            float w = __int_as_float(v.y);
            uint4 u = *(const uint4*)(hs + (size_t)(v.x & 0xFFFFF) * HC);
            f32x4 a0 = fp8x4_to_f32(u.x), a1 = fp8x4_to_f32(u.y);
            f32x4 a2 = fp8x4_to_f32(u.z), a3 = fp8x4_to_f32(u.w);
            #pragma unroll
            for (int k = 0; k < 4; ++k) {
                racc[k]      += w * a0[k];
                racc[k + 4]  += w * a1[k];
                racc[k + 8]  += w * a2[k];
                racc[k + 12] += w * a3[k];
            }
        }
        if (curd >= 0) {
            float* ap = &acc_sh[curd * 132 + ch * 16];
            #pragma unroll
            for (int k = 0; k < 16; ++k) atomicAdd(&ap[k], racc[k]);
        }
        __syncthreads();
    }

    // output: thread (nslot, ch) scales its node's 16 channels
    int nslot = tid >> 3;
    int n = blockIdx.y * 32 + nslot;     // Nn = 625*32 exactly
    float inv = dinv[n * 4 + head];
    bf16x8 o0, o1;
    #pragma unroll
    for (int k = 0; k < 8; ++k) {
        o0[k] = (__bf16)fmaxf(acc_sh[nslot * 132 + ch * 16 + k] * inv
                              + bias_l[slice * 128 + ch * 16 + k], 0.f);
        o1[k] = (__bf16)fmaxf(acc_sh[nslot * 132 + ch * 16 + 8 + k] * inv
                              + bias_l[slice * 128 + ch * 16 + 8 + k], 0.f);
    }
    *(bf16x8*)(outb + (size_t)n * HC + slice * 128 + ch * 16) = o0;
    *(bf16x8*)(outb + (size_t)n * HC + slice * 128 + ch * 16 + 8) = o1;
}

// ---------------- global mean pool (race-free partials) ----------------

__device__ __forceinline__ int lower_bound_batch(const int* __restrict__ batch, int val) {
    int lo = 0, hi = Nn;
    while (lo < hi) { int mid = (lo + hi) >> 1; if (batch[mid] < val) lo = mid + 1; else hi = mid; }
    return lo;
}

__global__ void pool_kernel(const __bf16* __restrict__ h2b, const int* __restrict__ batch,
                            float* __restrict__ pooledP) {
    int b = blockIdx.x, part = blockIdx.y;   // grid (B, 8)
    int tid = threadIdx.x;
    int start = lower_bound_batch(batch, b);
    int end   = lower_bound_batch(batch, b + 1);
    int len = end - start;
    int chunk = (len + 7) / 8;
    int s0 = start + part * chunk;
    int s1 = min(s0 + chunk, end);
    float acc[4] = {0.f, 0.f, 0.f, 0.f};
    for (int n = s0; n < s1; ++n) {
        bf16x4 v = ((const bf16x4*)(h2b + (size_t)n * HC))[tid];
        #pragma unroll
        for (int k = 0; k < 4; ++k) acc[k] += (float)v[k];
    }
    #pragma unroll
    for (int k = 0; k < 4; ++k)
        pooledP[((size_t)part * Bb + b) * HC + tid * 4 + k] = acc[k];
}

// ---------------- projection (k-split, race-free partials) + layernorm ----------------

__global__ __launch_bounds__(512) void proj_partial_kernel(const float* __restrict__ pooledP,
                                                           const int* __restrict__ batch,
                                                           const float* __restrict__ projW,
                                                           float* __restrict__ projP) {
    int b = blockIdx.x, part = blockIdx.y;   // grid (16, 8)
    int d = threadIdx.x;                     // 512
    __shared__ float psum[HC];
    int start = lower_bound_batch(batch, b);
    int end   = lower_bound_batch(batch, b + 1);
    float inv = 1.0f / fmaxf((float)(end - start), 1.0f);
    for (int k = d; k < HC; k += 512) {
        float s = 0.f;
        #pragma unroll
        for (int p = 0; p < 8; ++p) s += pooledP[((size_t)p * Bb + b) * HC + k];
        psum[k] = s * inv;
    }
    __syncthreads();
    float acc = 0.f;
    int k0 = part * 128;
    for (int k = k0; k < k0 + 128; ++k)
        acc += psum[k] * projW[(size_t)k * Dd + d];
    projP[((size_t)part * Bb + b) * Dd + d] = acc;
}

__global__ __launch_bounds__(512) void ln_kernel(const float* __restrict__ projP,
                                                 const float* __restrict__ projb,
                                                 const float* __restrict__ gamma,
                                                 const float* __restrict__ beta,
                                                 float* __restrict__ out) {
    int b = blockIdx.x;
    int d = threadIdx.x;
    __shared__ float red[512];
    float o = projb[d];
    #pragma unroll
    for (int p = 0; p < 8; ++p) o += projP[((size_t)p * Bb + b) * Dd + d];
    red[d] = o;
    __syncthreads();
    for (int off = 256; off > 0; off >>= 1) {
        if (d < off) red[d] += red[d + off];
        __syncthreads();
    }
    float mu = red[0] / (float)Dd;
    __syncthreads();
    float df = o - mu;
    red[d] = df * df;
    __syncthreads();
    for (int off = 256; off > 0; off >>= 1) {
        if (d < off) red[d] += red[d + off];
        __syncthreads();
    }
    float var = red[0] / (float)Dd;
    out[b * Dd + d] = df / sqrtf(var + LN_EPS) * gamma[d] + beta[d];
}

// ---------------- launch ----------------

extern "C" void kernel_launch(void* const* d_in, const int* in_sizes, int n_in,
                              void* d_out, int out_size, void* d_ws, size_t ws_size,
                              hipStream_t stream) {
    const float* x         = (const float*)d_in[0];
    const int*   ei        = (const int*)d_in[1];
    const int*   batch     = (const int*)d_in[2];
    const float* W0        = (const float*)d_in[3];
    const float* W_rest    = (const float*)d_in[4];
    const float* att_src   = (const float*)d_in[5];
    const float* att_dst   = (const float*)d_in[6];
    const float* conv_bias = (const float*)d_in[7];
    const float* proj_W    = (const float*)d_in[8];
    const float* proj_b    = (const float*)d_in[9];
    const float* ln_gamma  = (const float*)d_in[10];
    const float* ln_beta   = (const float*)d_in[11];
    float* out = (float*)d_out;

    char* ws = (char*)d_ws;
    size_t off = 0;
    auto alloc = [&](size_t bytes) {
        void* p = ws + off;
        off = (off + bytes + 255) & ~(size_t)255;
        return p;
    };
    unsigned char* h8 = (unsigned char*)alloc((size_t)Nn * HC);   // GEMM out (fp8, agg payload)
    __bf16* h2b     = (__bf16*)alloc((size_t)Nn * HC * 2);        // layer out (bf16)
    __bf16* xb      = (__bf16*)alloc((size_t)Nn * Dd * 2);
    __bf16* W0T     = (__bf16*)alloc((size_t)HC * Dd * 2);
    __bf16* WrT     = (__bf16*)alloc((size_t)3 * HC * HC * 2);
    float*  aprt_s  = (float*)alloc((size_t)4 * Nn * Hh * 4);     // alpha partials
    float*  aprt_d  = (float*)alloc((size_t)4 * Nn * Hh * 4);
    float*  asrc    = (float*)alloc((size_t)Nn * Hh * 4);
    float*  adst    = (float*)alloc((size_t)Nn * Hh * 4);
    float*  ewT     = (float*)alloc((size_t)Hh * ETOT * 4);       // head-major
    float*  dinv    = (float*)alloc((size_t)Nn * Hh * 4);
    int*    deg     = (int*)alloc((size_t)Nn * 4);
    int*    tmp     = (int*)alloc((size_t)Nn * 4);
    int*    bsum    = (int*)alloc((size_t)256 * 4);
    int*    row_ptr = (int*)alloc((size_t)(Nn + 1) * 4);
    int*    cursor  = (int*)alloc((size_t)Nn * 4);
    int*    csr_src = (int*)alloc((size_t)ETOT * 4);
    float*  pooledP = (float*)alloc((size_t)8 * Bb * HC * 4);
    float*  projP   = (float*)alloc((size_t)8 * Bb * Dd * 4);
    (void)ws_size; (void)in_sizes; (void)n_in; (void)out_size;

    // ---- build CSR by destination ----
    hipMemsetAsync(deg, 0, (size_t)Nn * 4, stream);
    count_deg_kernel<<<(ETOT + 255) / 256, 256, 0, stream>>>(ei, deg);
    scan1_kernel<<<NBLK, 256, 0, stream>>>(deg, tmp, bsum);
    scan2_kernel<<<1, 256, 0, stream>>>(bsum);
    scan3_kernel<<<NBLK, 256, 0, stream>>>(tmp, bsum, deg, row_ptr, cursor);
    scatter_kernel<<<(ETOT + 255) / 256, 256, 0, stream>>>(ei, cursor, csr_src);

    // ---- bf16 casts / weight transposes ----
    cast_kernel<<<(Nn * Dd / 4 + 255) / 256, 256, 0, stream>>>(x, xb, Nn * Dd / 4);
    transpose_cast_kernel<<<dim3(HC / 32, Dd / 32, 1), dim3(32, 8), 0, stream>>>(W0, W0T, Dd, HC);
    transpose_cast_kernel<<<dim3(HC / 32, HC / 32, 3), dim3(32, 8), 0, stream>>>(W_rest, WrT, HC, HC);

    // ---- GAT layers ----
    dim3 gemm_grid(8, 160);   // 1280 swizzled ids -> (157 row-blocks, 8 col-blocks)
    for (int l = 0; l < Ll; ++l) {
        const __bf16* Afeat = (l == 0) ? xb : h2b;
        int K = (l == 0) ? Dd : HC;
        const __bf16* BT = (l == 0) ? W0T : (WrT + (size_t)(l - 1) * HC * HC);
        mfma_gemm_kernel<<<gemm_grid, 256, 0, stream>>>(
            Afeat, BT, h8, att_src + l * HC, att_dst + l * HC, aprt_s, aprt_d, Nn, K);
        alpha_sum_kernel<<<NBLK, 256, 0, stream>>>(aprt_s, aprt_d, asrc, adst);
        ew_kernel<<<(Nn + 15) / 16, 256, 0, stream>>>(asrc, adst, row_ptr, csr_src, ewT, dinv);
        agg_slice_kernel<<<dim3(8, Nn / 32), 256, 0, stream>>>(
            h8, ewT, dinv, row_ptr, csr_src, conv_bias + l * HC, h2b);
    }

    // ---- pool + proj + layernorm (all race-free partials, no memsets) ----
    pool_kernel<<<dim3(Bb, 8), 256, 0, stream>>>(h2b, batch, pooledP);
    proj_partial_kernel<<<dim3(Bb, 8), 512, 0, stream>>>(pooledP, batch, proj_W, projP);
    ln_kernel<<<Bb, 512, 0, stream>>>(projP, proj_b, ln_gamma, ln_beta, out);
}

// Round 7
// 649.657 us; speedup vs baseline: 1.8121x; 1.8121x over previous
//
#include <hip/hip_runtime.h>
#include <hip/hip_bf16.h>
#include <hip/hip_fp8.h>
#include <math.h>

#define Nn 20000
#define Ee 320000
#define Dd 512
#define Hh 4
#define Cc 256
#define Ll 4
#define Bb 16
#define HC 1024               // H*C
#define ETOT (Ee + Nn)        // edges + self loops = 340000
#define NEG_SLOPE 0.2f
#define LN_EPS 1e-5f
#define NBLK ((Nn + 255) / 256)   // 79 scan blocks

typedef __attribute__((ext_vector_type(8))) __bf16 bf16x8;
typedef __attribute__((ext_vector_type(4))) __bf16 bf16x4;
typedef __attribute__((ext_vector_type(4))) float f32x4;
typedef __attribute__((ext_vector_type(2))) float f32x2;

// fp8 e4m3 (OCP) x4 decode — HW packed cvt if available
__device__ __forceinline__ f32x4 fp8x4_to_f32(unsigned int v) {
#if __has_builtin(__builtin_amdgcn_cvt_pk_f32_fp8)
    f32x2 lo = __builtin_amdgcn_cvt_pk_f32_fp8((int)v, false);
    f32x2 hi = __builtin_amdgcn_cvt_pk_f32_fp8((int)v, true);
    f32x4 r; r[0] = lo[0]; r[1] = lo[1]; r[2] = hi[0]; r[3] = hi[1];
    return r;
#else
    f32x4 r;
    #pragma unroll
    for (int i = 0; i < 4; ++i) {
        __hip_fp8_e4m3 q; q.__x = (v >> (8 * i)) & 0xff;
        r[i] = (float)q;
    }
    return r;
#endif
}

__device__ __forceinline__ unsigned char f32_to_fp8(float f) {
    return __hip_fp8_e4m3(f).__x;
}

// ---------------- CSR build ----------------

__device__ __forceinline__ void decode_edge(const int* ei, int e, int& s, int& d) {
    if (e < Ee) { s = ei[e]; d = ei[Ee + e]; }
    else        { s = e - Ee; d = e - Ee; }   // self loop
}

__global__ void count_deg_kernel(const int* __restrict__ ei, int* __restrict__ deg) {
    int e = blockIdx.x * blockDim.x + threadIdx.x;
    if (e >= ETOT) return;
    int s, d; decode_edge(ei, e, s, d);
    atomicAdd(&deg[d], 1);
}

__global__ void scan1_kernel(const int* __restrict__ deg, int* __restrict__ tmp,
                             int* __restrict__ bsum) {
    __shared__ int sd[256];
    int tid = threadIdx.x;
    int i = blockIdx.x * 256 + tid;
    sd[tid] = (i < Nn) ? deg[i] : 0;
    __syncthreads();
    for (int off = 1; off < 256; off <<= 1) {
        int t = (tid >= off) ? sd[tid - off] : 0;
        __syncthreads();
        sd[tid] += t;
        __syncthreads();
    }
    if (i < Nn) tmp[i] = sd[tid];
    if (tid == 255) bsum[blockIdx.x] = sd[255];
}

__global__ void scan2_kernel(int* __restrict__ bsum) {   // single block, NBLK<=256
    __shared__ int sd[256];
    int tid = threadIdx.x;
    sd[tid] = (tid < NBLK) ? bsum[tid] : 0;
    __syncthreads();
    for (int off = 1; off < 256; off <<= 1) {
        int t = (tid >= off) ? sd[tid - off] : 0;
        __syncthreads();
        sd[tid] += t;
        __syncthreads();
    }
    if (tid < NBLK) bsum[tid] = sd[tid];
}

__global__ void scan3_kernel(const int* __restrict__ tmp, const int* __restrict__ bsum,
                             const int* __restrict__ deg,
                             int* __restrict__ row_ptr, int* __restrict__ cursor) {
    int i = blockIdx.x * 256 + threadIdx.x;
    if (i >= Nn) return;
    int boff = (blockIdx.x == 0) ? 0 : bsum[blockIdx.x - 1];
    int incl = tmp[i] + boff;
    row_ptr[i + 1] = incl;
    cursor[i] = incl - deg[i];
    if (i == 0) row_ptr[0] = 0;
}

__global__ void scatter_kernel(const int* __restrict__ ei, int* __restrict__ cursor,
                               int* __restrict__ csr_src) {
    int e = blockIdx.x * blockDim.x + threadIdx.x;
    if (e >= ETOT) return;
    int s, d; decode_edge(ei, e, s, d);
    int pos = atomicAdd(&cursor[d], 1);
    csr_src[pos] = s;
}

// ---------------- casts ----------------

__global__ void cast_kernel(const float* __restrict__ in, __bf16* __restrict__ out, int n4) {
    int i = blockIdx.x * blockDim.x + threadIdx.x;
    if (i >= n4) return;
    f32x4 v = ((const f32x4*)in)[i];
    bf16x4 o;
    #pragma unroll
    for (int k = 0; k < 4; ++k) o[k] = (__bf16)v[k];
    ((bf16x4*)out)[i] = o;
}

// W[K][N] fp32 -> WT[N][K] bf16; grid.z selects matrix (stride K*N)
__global__ void transpose_cast_kernel(const float* __restrict__ W, __bf16* __restrict__ WT,
                                      int K, int N) {
    __shared__ float tile[32][33];
    W  += (size_t)blockIdx.z * K * N;
    WT += (size_t)blockIdx.z * K * N;
    int n0 = blockIdx.x * 32, k0 = blockIdx.y * 32;
    for (int i = threadIdx.y; i < 32; i += 8)
        tile[i][threadIdx.x] = W[(size_t)(k0 + i) * N + n0 + threadIdx.x];
    __syncthreads();
    for (int i = threadIdx.y; i < 32; i += 8)
        WT[(size_t)(n0 + i) * K + k0 + threadIdx.x] = (__bf16)tile[threadIdx.x][i];
}

// ---------------- MFMA GEMM + fused alpha epilogue (r0 VERBATIM — proven 65us) ----------
// C8[M,1024](fp8) = A[M,K](bf16) @ BT[1024,K]^T. XCD swizzle (r11: FETCH 162->34MB).
// r18 note: r15/r16/r17 all tried intra-block pipelining and ALL regressed; this
// 32KB-LDS structure at 2+ blocks/CU is the empirical local optimum — frozen.
// Epilogue computes alpha partials ps/pd from IN-REGISTER h (zero extra traffic).
// Race-free: part=(cblk&1)*2+(wave&1).

__device__ __forceinline__ void async16(const __bf16* g, __bf16* l) {
    __builtin_amdgcn_global_load_lds((const __attribute__((address_space(1))) void*)g,
                                     (__attribute__((address_space(3))) void*)l,
                                     16, 0, 0);
}

__global__ __launch_bounds__(256) void mfma_gemm_kernel(
    const __bf16* __restrict__ A,   // [M][K]
    const __bf16* __restrict__ BT,  // [1024][K]
    unsigned char* __restrict__ C8, // [M][1024] fp8 e4m3 (agg gather payload)
    const float* __restrict__ att_s,  // [4][256] this layer
    const float* __restrict__ att_d,  // [4][256]
    float* __restrict__ aprt_s,     // [4][M][4] partials (race-free)
    float* __restrict__ aprt_d,     // [4][M][4]
    int M, int K)
{
    int lin = blockIdx.y * 8 + blockIdx.x;          // grid (8, 160) -> 1280 ids
    int rblk = (lin >> 6) * 8 + (lin & 7);
    int cblk = (lin >> 3) & 7;
    int rowBase = rblk * 128, colBase = cblk * 128;
    if (rowBase >= M) return;

    __shared__ __bf16 As[2][128 * 32];
    __shared__ __bf16 Bs[2][128 * 32];
    int tid = threadIdx.x;
    int wave = tid >> 6, lane = tid & 63;
    int m16 = lane & 15, quad = lane >> 4;
    int waveRow = (wave >> 1) * 64, waveCol = (wave & 1) * 64;

    f32x4 acc[4][4] = {};

    int srow = wave * 32 + (lane >> 2);          // staging row, +16 for second half
    int gch0 = (lane & 3) ^ ((srow >> 1) & 3);
    int gch1 = (lane & 3) ^ (((srow + 16) >> 1) & 3);
    int gr0 = rowBase + srow;       if (gr0 >= M) gr0 = M - 1;
    int gr1 = rowBase + srow + 16;  if (gr1 >= M) gr1 = M - 1;
    int ldsOff = srow * 32 + (lane & 3) * 8;

    for (int k0 = 0; k0 < K; k0 += 64) {
        #pragma unroll
        for (int p = 0; p < 2; ++p) {
            int kp = k0 + p * 32;
            async16(A + (size_t)gr0 * K + kp + gch0 * 8, &As[p][ldsOff]);
            async16(A + (size_t)gr1 * K + kp + gch1 * 8, &As[p][ldsOff + 16 * 32]);
            async16(BT + (size_t)(colBase + srow) * K + kp + gch0 * 8, &Bs[p][ldsOff]);
            async16(BT + (size_t)(colBase + srow + 16) * K + kp + gch1 * 8, &Bs[p][ldsOff + 16 * 32]);
        }
        __syncthreads();
        #pragma unroll
        for (int p = 0; p < 2; ++p) {
            bf16x8 af[4], bfr[4];
            #pragma unroll
            for (int i = 0; i < 4; ++i) {
                int row = waveRow + i * 16 + m16;
                af[i] = *(const bf16x8*)&As[p][row * 32 + (quad ^ ((row >> 1) & 3)) * 8];
                int col = waveCol + i * 16 + m16;
                bfr[i] = *(const bf16x8*)&Bs[p][col * 32 + (quad ^ ((col >> 1) & 3)) * 8];
            }
            #pragma unroll
            for (int i = 0; i < 4; ++i)
                #pragma unroll
                for (int j = 0; j < 4; ++j)
                    acc[i][j] = __builtin_amdgcn_mfma_f32_16x16x32_bf16(af[i], bfr[j], acc[i][j], 0, 0, 0);
        }
        __syncthreads();
    }

    // att weights for this wave's 64-col span (single head: span never crosses 256)
    int cbase = colBase + waveCol;
    int head = cbase >> 8;
    int part = (cblk & 1) * 2 + (wave & 1);
    float as4[4], ad4[4];
    #pragma unroll
    for (int j = 0; j < 4; ++j) {
        int off = (cbase + j * 16 + m16) & 255;
        as4[j] = att_s[head * 256 + off];
        ad4[j] = att_d[head * 256 + off];
    }

    // fp8 stores (C/D layout: col=lane&15, row=quad*4+reg) + alpha partials
    #pragma unroll
    for (int i = 0; i < 4; ++i) {
        int r0 = rowBase + waveRow + i * 16 + quad * 4;
        #pragma unroll
        for (int r = 0; r < 4; ++r) {
            int row = r0 + r;
            float ps = 0.f, pd = 0.f;
            #pragma unroll
            for (int j = 0; j < 4; ++j) {
                float h = acc[i][j][r];
                ps += h * as4[j];
                pd += h * ad4[j];
                if (row < M)
                    C8[(size_t)row * HC + colBase + waveCol + j * 16 + m16] = f32_to_fp8(h);
            }
            #pragma unroll
            for (int off = 1; off < 16; off <<= 1) {
                ps += __shfl_xor(ps, off);
                pd += __shfl_xor(pd, off);
            }
            if (m16 == 0 && row < M) {
                aprt_s[((size_t)part * M + row) * 4 + head] = ps;
                aprt_d[((size_t)part * M + row) * 4 + head] = pd;
            }
        }
    }
}

// ---------------- alpha partial reduce: asrc/adst[n] = sum over 4 parts ----------------

__global__ void alpha_sum_kernel(const float* __restrict__ aprt_s,
                                 const float* __restrict__ aprt_d,
                                 float* __restrict__ asrc, float* __restrict__ adst) {
    int n = blockIdx.x * 256 + threadIdx.x;
    if (n >= Nn) return;
    f32x4 s = {0.f, 0.f, 0.f, 0.f}, d = {0.f, 0.f, 0.f, 0.f};
    #pragma unroll
    for (int p = 0; p < 4; ++p) {
        f32x4 vs = ((const f32x4*)aprt_s)[(size_t)p * Nn + n];
        f32x4 vd = ((const f32x4*)aprt_d)[(size_t)p * Nn + n];
        #pragma unroll
        for (int k = 0; k < 4; ++k) { s[k] += vs[k]; d[k] += vd[k]; }
    }
    ((f32x4*)asrc)[n] = s;
    ((f32x4*)adst)[n] = d;
}

// ---------------- edge-weight precompute (head-major output) ----------------
// r19: 16 lanes/node (avg degree 17 -> ~70% lane util, ~10000 wave-bodies).

__global__ __launch_bounds__(256) void ew_kernel(const float* __restrict__ asrc,
                                                 const float* __restrict__ adst,
                                                 const int* __restrict__ row_ptr,
                                                 const int* __restrict__ csr_src,
                                                 float* __restrict__ ewT,
                                                 float* __restrict__ dinv) {
    int grp = threadIdx.x >> 4, lane16 = threadIdx.x & 15;
    int n = blockIdx.x * 16 + grp;
    if (n >= Nn) return;
    int start = row_ptr[n], end = row_ptr[n + 1];
    f32x4 ad = ((const f32x4*)adst)[n];
    f32x4 d = {0.f, 0.f, 0.f, 0.f};
    for (int e = start + lane16; e < end; e += 16) {
        int s = csr_src[e];
        f32x4 as = ((const f32x4*)asrc)[s];
        #pragma unroll
        for (int k = 0; k < 4; ++k) {
            float z = as[k] + ad[k];
            z = (z > 0.f) ? z : NEG_SLOPE * z;
            float ex = __expf(z);
            ewT[(size_t)k * ETOT + e] = ex;
            d[k] += ex;
        }
    }
    #pragma unroll
    for (int off = 8; off > 0; off >>= 1) {
        #pragma unroll
        for (int k = 0; k < 4; ++k) d[k] += __shfl_xor(d[k], off);
    }
    if (lane16 == 0) {
        f32x4 iv;
        #pragma unroll
        for (int k = 0; k < 4; ++k) iv[k] = 1.f / (d[k] + 1e-16f);
        ((f32x4*)dinv)[n] = iv;
    }
}

// ---------------- sliced aggregation — r21: r19 structure + parity sub-group split ------
// r20 post-mortem: balanced-window + ds_add flushes = 1.96M bank conflicts, 189us
// (atomics confounded the balance test). r21 reverts to the r19 per-node walk
// (known-good) with ONE change: each node gets TWO 8-lane sub-groups splitting its
// edge list by parity (e += 2). Serial straggler depth per wave ~26 -> ~13 dependent
// L2-latency iterations. Partials merge once per node via plain LDS (no atomics,
// no hot-loop branches). FP delta: one extra partial-sum merge (~1e-7 rel).
// grid (8, 1250): slice -> XCD affinity kept (per-XCD footprint 2.5MB, r10).

__global__ __launch_bounds__(256) void agg_slice_kernel(
    const unsigned char* __restrict__ h8,
    const float* __restrict__ ewT,
    const float* __restrict__ dinv,
    const int* __restrict__ row_ptr,
    const int* __restrict__ csr_src,
    const float* __restrict__ bias_l,
    __bf16* __restrict__ outb)
{
    int slice = blockIdx.x;              // 0..7
    int head = slice >> 1;
    int tid = threadIdx.x;
    int nslot = tid >> 4;                // 0..15 node slot
    int sub   = (tid >> 3) & 1;          // parity sub-group
    int ch    = tid & 7;                 // 16B fp8 group within 128B slice
    int n = blockIdx.y * 16 + nslot;

    __shared__ int2  ce_sh[1024];        // (src, bitcast ew)
    __shared__ float mrg_sh[16 * 132];   // sub-1 partials (16 nodes x 128 + 4 pad)
    __shared__ int   rp_sh[17];

    if (tid < 17) rp_sh[tid] = row_ptr[blockIdx.y * 16 + tid];
    __syncthreads();
    int blk_lo = rp_sh[0], blk_hi = rp_sh[16];
    int start = rp_sh[nslot], end = rp_sh[nslot + 1];

    const unsigned char* hs = h8 + slice * 128 + ch * 16;
    const float* ewh = ewT + (size_t)head * ETOT;
    f32x4 acc4[4] = {};

    for (int c0 = blk_lo; c0 < blk_hi; c0 += 1024) {
        int c1 = min(c0 + 1024, blk_hi);
        int cnt = c1 - c0;
        for (int i = tid; i < cnt; i += 256) {     // coalesced stage
            int2 v;
            v.x = csr_src[c0 + i];
            v.y = __float_as_int(ewh[c0 + i]);
            ce_sh[i] = v;
        }
        __syncthreads();
        int lo = max(start, c0), hi = min(end, c1);
        for (int e = lo + sub; e < hi; e += 2) {
            int2 v = ce_sh[e - c0];
            float w = __int_as_float(v.y);
            uint4 u = *(const uint4*)(hs + (size_t)v.x * HC);
            acc4[0] += fp8x4_to_f32(u.x) * w;
            acc4[1] += fp8x4_to_f32(u.y) * w;
            acc4[2] += fp8x4_to_f32(u.z) * w;
            acc4[3] += fp8x4_to_f32(u.w) * w;
        }
        __syncthreads();
    }

    // merge parity halves via LDS (non-atomic, once per node)
    if (sub) {
        #pragma unroll
        for (int j = 0; j < 4; ++j)
            *(f32x4*)&mrg_sh[nslot * 132 + ch * 16 + j * 4] = acc4[j];
    }
    __syncthreads();
    if (!sub) {
        float inv = dinv[n * 4 + head];
        bf16x8 o0, o1;
        #pragma unroll
        for (int j = 0; j < 4; ++j) {
            f32x4 m = *(const f32x4*)&mrg_sh[nslot * 132 + ch * 16 + j * 4];
            acc4[j] += m;
        }
        #pragma unroll
        for (int k = 0; k < 4; ++k) {
            o0[k]     = (__bf16)fmaxf(acc4[0][k] * inv + bias_l[slice * 128 + ch * 16 + k], 0.f);
            o0[k + 4] = (__bf16)fmaxf(acc4[1][k] * inv + bias_l[slice * 128 + ch * 16 + 4 + k], 0.f);
            o1[k]     = (__bf16)fmaxf(acc4[2][k] * inv + bias_l[slice * 128 + ch * 16 + 8 + k], 0.f);
            o1[k + 4] = (__bf16)fmaxf(acc4[3][k] * inv + bias_l[slice * 128 + ch * 16 + 12 + k], 0.f);
        }
        *(bf16x8*)(outb + (size_t)n * HC + slice * 128 + ch * 16) = o0;
        *(bf16x8*)(outb + (size_t)n * HC + slice * 128 + ch * 16 + 8) = o1;
    }
}

// ---------------- global mean pool (race-free partials) ----------------

__device__ __forceinline__ int lower_bound_batch(const int* __restrict__ batch, int val) {
    int lo = 0, hi = Nn;
    while (lo < hi) { int mid = (lo + hi) >> 1; if (batch[mid] < val) lo = mid + 1; else hi = mid; }
    return lo;
}

__global__ void pool_kernel(const __bf16* __restrict__ h2b, const int* __restrict__ batch,
                            float* __restrict__ pooledP) {
    int b = blockIdx.x, part = blockIdx.y;   // grid (B, 8)
    int tid = threadIdx.x;
    int start = lower_bound_batch(batch, b);
    int end   = lower_bound_batch(batch, b + 1);
    int len = end - start;
    int chunk = (len + 7) / 8;
    int s0 = start + part * chunk;
    int s1 = min(s0 + chunk, end);
    float acc[4] = {0.f, 0.f, 0.f, 0.f};
    for (int n = s0; n < s1; ++n) {
        bf16x4 v = ((const bf16x4*)(h2b + (size_t)n * HC))[tid];
        #pragma unroll
        for (int k = 0; k < 4; ++k) acc[k] += (float)v[k];
    }
    #pragma unroll
    for (int k = 0; k < 4; ++k)
        pooledP[((size_t)part * Bb + b) * HC + tid * 4 + k] = acc[k];
}

// ---------------- projection (k-split, race-free partials) + layernorm ----------------

__global__ __launch_bounds__(512) void proj_partial_kernel(const float* __restrict__ pooledP,
                                                           const int* __restrict__ batch,
                                                           const float* __restrict__ projW,
                                                           float* __restrict__ projP) {
    int b = blockIdx.x, part = blockIdx.y;   // grid (16, 8)
    int d = threadIdx.x;                     // 512
    __shared__ float psum[HC];
    int start = lower_bound_batch(batch, b);
    int end   = lower_bound_batch(batch, b + 1);
    float inv = 1.0f / fmaxf((float)(end - start), 1.0f);
    for (int k = d; k < HC; k += 512) {
        float s = 0.f;
        #pragma unroll
        for (int p = 0; p < 8; ++p) s += pooledP[((size_t)p * Bb + b) * HC + k];
        psum[k] = s * inv;
    }
    __syncthreads();
    float acc = 0.f;
    int k0 = part * 128;
    for (int k = k0; k < k0 + 128; ++k)
        acc += psum[k] * projW[(size_t)k * Dd + d];
    projP[((size_t)part * Bb + b) * Dd + d] = acc;
}

__global__ __launch_bounds__(512) void ln_kernel(const float* __restrict__ projP,
                                                 const float* __restrict__ projb,
                                                 const float* __restrict__ gamma,
                                                 const float* __restrict__ beta,
                                                 float* __restrict__ out) {
    int b = blockIdx.x;
    int d = threadIdx.x;
    __shared__ float red[512];
    float o = projb[d];
    #pragma unroll
    for (int p = 0; p < 8; ++p) o += projP[((size_t)p * Bb + b) * Dd + d];
    red[d] = o;
    __syncthreads();
    for (int off = 256; off > 0; off >>= 1) {
        if (d < off) red[d] += red[d + off];
        __syncthreads();
    }
    float mu = red[0] / (float)Dd;
    __syncthreads();
    float df = o - mu;
    red[d] = df * df;
    __syncthreads();
    for (int off = 256; off > 0; off >>= 1) {
        if (d < off) red[d] += red[d + off];
        __syncthreads();
    }
    float var = red[0] / (float)Dd;
    out[b * Dd + d] = df / sqrtf(var + LN_EPS) * gamma[d] + beta[d];
}

// ---------------- launch ----------------

extern "C" void kernel_launch(void* const* d_in, const int* in_sizes, int n_in,
                              void* d_out, int out_size, void* d_ws, size_t ws_size,
                              hipStream_t stream) {
    const float* x         = (const float*)d_in[0];
    const int*   ei        = (const int*)d_in[1];
    const int*   batch     = (const int*)d_in[2];
    const float* W0        = (const float*)d_in[3];
    const float* W_rest    = (const float*)d_in[4];
    const float* att_src   = (const float*)d_in[5];
    const float* att_dst   = (const float*)d_in[6];
    const float* conv_bias = (const float*)d_in[7];
    const float* proj_W    = (const float*)d_in[8];
    const float* proj_b    = (const float*)d_in[9];
    const float* ln_gamma  = (const float*)d_in[10];
    const float* ln_beta   = (const float*)d_in[11];
    float* out = (float*)d_out;

    char* ws = (char*)d_ws;
    size_t off = 0;
    auto alloc = [&](size_t bytes) {
        void* p = ws + off;
        off = (off + bytes + 255) & ~(size_t)255;
        return p;
    };
    unsigned char* h8 = (unsigned char*)alloc((size_t)Nn * HC);   // GEMM out (fp8, agg payload)
    __bf16* h2b     = (__bf16*)alloc((size_t)Nn * HC * 2);        // layer out (bf16)
    __bf16* xb      = (__bf16*)alloc((size_t)Nn * Dd * 2);
    __bf16* W0T     = (__bf16*)alloc((size_t)HC * Dd * 2);
    __bf16* WrT     = (__bf16*)alloc((size_t)3 * HC * HC * 2);
    float*  aprt_s  = (float*)alloc((size_t)4 * Nn * Hh * 4);     // alpha partials
    float*  aprt_d  = (float*)alloc((size_t)4 * Nn * Hh * 4);
    float*  asrc    = (float*)alloc((size_t)Nn * Hh * 4);
    float*  adst    = (float*)alloc((size_t)Nn * Hh * 4);
    float*  ewT     = (float*)alloc((size_t)Hh * ETOT * 4);       // head-major
    float*  dinv    = (float*)alloc((size_t)Nn * Hh * 4);
    int*    deg     = (int*)alloc((size_t)Nn * 4);
    int*    tmp     = (int*)alloc((size_t)Nn * 4);
    int*    bsum    = (int*)alloc((size_t)256 * 4);
    int*    row_ptr = (int*)alloc((size_t)(Nn + 1) * 4);
    int*    cursor  = (int*)alloc((size_t)Nn * 4);
    int*    csr_src = (int*)alloc((size_t)ETOT * 4);
    float*  pooledP = (float*)alloc((size_t)8 * Bb * HC * 4);
    float*  projP   = (float*)alloc((size_t)8 * Bb * Dd * 4);
    (void)ws_size; (void)in_sizes; (void)n_in; (void)out_size;

    // ---- build CSR by destination ----
    hipMemsetAsync(deg, 0, (size_t)Nn * 4, stream);
    count_deg_kernel<<<(ETOT + 255) / 256, 256, 0, stream>>>(ei, deg);
    scan1_kernel<<<NBLK, 256, 0, stream>>>(deg, tmp, bsum);
    scan2_kernel<<<1, 256, 0, stream>>>(bsum);
    scan3_kernel<<<NBLK, 256, 0, stream>>>(tmp, bsum, deg, row_ptr, cursor);
    scatter_kernel<<<(ETOT + 255) / 256, 256, 0, stream>>>(ei, cursor, csr_src);

    // ---- bf16 casts / weight transposes ----
    cast_kernel<<<(Nn * Dd / 4 + 255) / 256, 256, 0, stream>>>(x, xb, Nn * Dd / 4);
    transpose_cast_kernel<<<dim3(HC / 32, Dd / 32, 1), dim3(32, 8), 0, stream>>>(W0, W0T, Dd, HC);
    transpose_cast_kernel<<<dim3(HC / 32, HC / 32, 3), dim3(32, 8), 0, stream>>>(W_rest, WrT, HC, HC);

    // ---- GAT layers ----
    dim3 gemm_grid(8, 160);   // 1280 swizzled ids -> (157 row-blocks, 8 col-blocks)
    for (int l = 0; l < Ll; ++l) {
        const __bf16* Afeat = (l == 0) ? xb : h2b;
        int K = (l == 0) ? Dd : HC;
        const __bf16* BT = (l == 0) ? W0T : (WrT + (size_t)(l - 1) * HC * HC);
        mfma_gemm_kernel<<<gemm_grid, 256, 0, stream>>>(
            Afeat, BT, h8, att_src + l * HC, att_dst + l * HC, aprt_s, aprt_d, Nn, K);
        alpha_sum_kernel<<<NBLK, 256, 0, stream>>>(aprt_s, aprt_d, asrc, adst);
        ew_kernel<<<(Nn + 15) / 16, 256, 0, stream>>>(asrc, adst, row_ptr, csr_src, ewT, dinv);
        agg_slice_kernel<<<dim3(8, Nn / 16), 256, 0, stream>>>(
            h8, ewT, dinv, row_ptr, csr_src, conv_bias + l * HC, h2b);
    }

    // ---- pool + proj + layernorm (all race-free partials, no memsets) ----
    pool_kernel<<<dim3(Bb, 8), 256, 0, stream>>>(h2b, batch, pooledP);
    proj_partial_kernel<<<dim3(Bb, 8), 512, 0, stream>>>(pooledP, batch, proj_W, projP);
    ln_kernel<<<Bb, 512, 0, stream>>>(projP, proj_b, ln_gamma, ln_beta, out);
}

// Round 8
// 633.380 us; speedup vs baseline: 1.8587x; 1.0257x over previous
//
#include <hip/hip_runtime.h>
#include <hip/hip_bf16.h>
#include <hip/hip_fp8.h>
#include <math.h>

#define Nn 20000
#define Ee 320000
#define Dd 512
#define Hh 4
#define Cc 256
#define Ll 4
#define Bb 16
#define HC 1024               // H*C
#define ETOT (Ee + Nn)        // edges + self loops = 340000
#define NEG_SLOPE 0.2f
#define LN_EPS 1e-5f
#define NBLK ((Nn + 255) / 256)   // 79 scan blocks

typedef __attribute__((ext_vector_type(8))) __bf16 bf16x8;
typedef __attribute__((ext_vector_type(4))) __bf16 bf16x4;
typedef __attribute__((ext_vector_type(4))) float f32x4;
typedef __attribute__((ext_vector_type(2))) float f32x2;

// fp8 e4m3 (OCP) x4 decode — HW packed cvt if available
__device__ __forceinline__ f32x4 fp8x4_to_f32(unsigned int v) {
#if __has_builtin(__builtin_amdgcn_cvt_pk_f32_fp8)
    f32x2 lo = __builtin_amdgcn_cvt_pk_f32_fp8((int)v, false);
    f32x2 hi = __builtin_amdgcn_cvt_pk_f32_fp8((int)v, true);
    f32x4 r; r[0] = lo[0]; r[1] = lo[1]; r[2] = hi[0]; r[3] = hi[1];
    return r;
#else
    f32x4 r;
    #pragma unroll
    for (int i = 0; i < 4; ++i) {
        __hip_fp8_e4m3 q; q.__x = (v >> (8 * i)) & 0xff;
        r[i] = (float)q;
    }
    return r;
#endif
}

__device__ __forceinline__ unsigned char f32_to_fp8(float f) {
    return __hip_fp8_e4m3(f).__x;
}

// ---------------- CSR build ----------------

__device__ __forceinline__ void decode_edge(const int* ei, int e, int& s, int& d) {
    if (e < Ee) { s = ei[e]; d = ei[Ee + e]; }
    else        { s = e - Ee; d = e - Ee; }   // self loop
}

__global__ void count_deg_kernel(const int* __restrict__ ei, int* __restrict__ deg) {
    int e = blockIdx.x * blockDim.x + threadIdx.x;
    if (e >= ETOT) return;
    int s, d; decode_edge(ei, e, s, d);
    atomicAdd(&deg[d], 1);
}

__global__ void scan1_kernel(const int* __restrict__ deg, int* __restrict__ tmp,
                             int* __restrict__ bsum) {
    __shared__ int sd[256];
    int tid = threadIdx.x;
    int i = blockIdx.x * 256 + tid;
    sd[tid] = (i < Nn) ? deg[i] : 0;
    __syncthreads();
    for (int off = 1; off < 256; off <<= 1) {
        int t = (tid >= off) ? sd[tid - off] : 0;
        __syncthreads();
        sd[tid] += t;
        __syncthreads();
    }
    if (i < Nn) tmp[i] = sd[tid];
    if (tid == 255) bsum[blockIdx.x] = sd[255];
}

__global__ void scan2_kernel(int* __restrict__ bsum) {   // single block, NBLK<=256
    __shared__ int sd[256];
    int tid = threadIdx.x;
    sd[tid] = (tid < NBLK) ? bsum[tid] : 0;
    __syncthreads();
    for (int off = 1; off < 256; off <<= 1) {
        int t = (tid >= off) ? sd[tid - off] : 0;
        __syncthreads();
        sd[tid] += t;
        __syncthreads();
    }
    if (tid < NBLK) bsum[tid] = sd[tid];
}

__global__ void scan3_kernel(const int* __restrict__ tmp, const int* __restrict__ bsum,
                             const int* __restrict__ deg,
                             int* __restrict__ row_ptr, int* __restrict__ cursor) {
    int i = blockIdx.x * 256 + threadIdx.x;
    if (i >= Nn) return;
    int boff = (blockIdx.x == 0) ? 0 : bsum[blockIdx.x - 1];
    int incl = tmp[i] + boff;
    row_ptr[i + 1] = incl;
    cursor[i] = incl - deg[i];
    if (i == 0) row_ptr[0] = 0;
}

__global__ void scatter_kernel(const int* __restrict__ ei, int* __restrict__ cursor,
                               int* __restrict__ csr_src) {
    int e = blockIdx.x * blockDim.x + threadIdx.x;
    if (e >= ETOT) return;
    int s, d; decode_edge(ei, e, s, d);
    int pos = atomicAdd(&cursor[d], 1);
    csr_src[pos] = s;
}

// ---------------- casts ----------------

__global__ void cast_kernel(const float* __restrict__ in, __bf16* __restrict__ out, int n4) {
    int i = blockIdx.x * blockDim.x + threadIdx.x;
    if (i >= n4) return;
    f32x4 v = ((const f32x4*)in)[i];
    bf16x4 o;
    #pragma unroll
    for (int k = 0; k < 4; ++k) o[k] = (__bf16)v[k];
    ((bf16x4*)out)[i] = o;
}

// W[K][N] fp32 -> WT[N][K] bf16; grid.z selects matrix (stride K*N)
__global__ void transpose_cast_kernel(const float* __restrict__ W, __bf16* __restrict__ WT,
                                      int K, int N) {
    __shared__ float tile[32][33];
    W  += (size_t)blockIdx.z * K * N;
    WT += (size_t)blockIdx.z * K * N;
    int n0 = blockIdx.x * 32, k0 = blockIdx.y * 32;
    for (int i = threadIdx.y; i < 32; i += 8)
        tile[i][threadIdx.x] = W[(size_t)(k0 + i) * N + n0 + threadIdx.x];
    __syncthreads();
    for (int i = threadIdx.y; i < 32; i += 8)
        WT[(size_t)(n0 + i) * K + k0 + threadIdx.x] = (__bf16)tile[threadIdx.x][i];
}

// ---------------- MFMA GEMM + fused alpha epilogue (r0 VERBATIM — proven 65us) ----------
// C8[M,1024](fp8) = A[M,K](bf16) @ BT[1024,K]^T. XCD swizzle (r11: FETCH 162->34MB).
// FROZEN: r15/r16/r17 intra-block pipelining all regressed (98/83/77 vs 65us);
// 32KB-LDS structure at 2+ blocks/CU is the empirical local optimum (m114
// inter-block overlap > intra-block pipelining here).
// Epilogue computes alpha partials ps/pd from IN-REGISTER h (zero extra traffic).
// Race-free: part=(cblk&1)*2+(wave&1).

__device__ __forceinline__ void async16(const __bf16* g, __bf16* l) {
    __builtin_amdgcn_global_load_lds((const __attribute__((address_space(1))) void*)g,
                                     (__attribute__((address_space(3))) void*)l,
                                     16, 0, 0);
}

__global__ __launch_bounds__(256) void mfma_gemm_kernel(
    const __bf16* __restrict__ A,   // [M][K]
    const __bf16* __restrict__ BT,  // [1024][K]
    unsigned char* __restrict__ C8, // [M][1024] fp8 e4m3 (agg gather payload)
    const float* __restrict__ att_s,  // [4][256] this layer
    const float* __restrict__ att_d,  // [4][256]
    float* __restrict__ aprt_s,     // [4][M][4] partials (race-free)
    float* __restrict__ aprt_d,     // [4][M][4]
    int M, int K)
{
    int lin = blockIdx.y * 8 + blockIdx.x;          // grid (8, 160) -> 1280 ids
    int rblk = (lin >> 6) * 8 + (lin & 7);
    int cblk = (lin >> 3) & 7;
    int rowBase = rblk * 128, colBase = cblk * 128;
    if (rowBase >= M) return;

    __shared__ __bf16 As[2][128 * 32];
    __shared__ __bf16 Bs[2][128 * 32];
    int tid = threadIdx.x;
    int wave = tid >> 6, lane = tid & 63;
    int m16 = lane & 15, quad = lane >> 4;
    int waveRow = (wave >> 1) * 64, waveCol = (wave & 1) * 64;

    f32x4 acc[4][4] = {};

    int srow = wave * 32 + (lane >> 2);          // staging row, +16 for second half
    int gch0 = (lane & 3) ^ ((srow >> 1) & 3);
    int gch1 = (lane & 3) ^ (((srow + 16) >> 1) & 3);
    int gr0 = rowBase + srow;       if (gr0 >= M) gr0 = M - 1;
    int gr1 = rowBase + srow + 16;  if (gr1 >= M) gr1 = M - 1;
    int ldsOff = srow * 32 + (lane & 3) * 8;

    for (int k0 = 0; k0 < K; k0 += 64) {
        #pragma unroll
        for (int p = 0; p < 2; ++p) {
            int kp = k0 + p * 32;
            async16(A + (size_t)gr0 * K + kp + gch0 * 8, &As[p][ldsOff]);
            async16(A + (size_t)gr1 * K + kp + gch1 * 8, &As[p][ldsOff + 16 * 32]);
            async16(BT + (size_t)(colBase + srow) * K + kp + gch0 * 8, &Bs[p][ldsOff]);
            async16(BT + (size_t)(colBase + srow + 16) * K + kp + gch1 * 8, &Bs[p][ldsOff + 16 * 32]);
        }
        __syncthreads();
        #pragma unroll
        for (int p = 0; p < 2; ++p) {
            bf16x8 af[4], bfr[4];
            #pragma unroll
            for (int i = 0; i < 4; ++i) {
                int row = waveRow + i * 16 + m16;
                af[i] = *(const bf16x8*)&As[p][row * 32 + (quad ^ ((row >> 1) & 3)) * 8];
                int col = waveCol + i * 16 + m16;
                bfr[i] = *(const bf16x8*)&Bs[p][col * 32 + (quad ^ ((col >> 1) & 3)) * 8];
            }
            #pragma unroll
            for (int i = 0; i < 4; ++i)
                #pragma unroll
                for (int j = 0; j < 4; ++j)
                    acc[i][j] = __builtin_amdgcn_mfma_f32_16x16x32_bf16(af[i], bfr[j], acc[i][j], 0, 0, 0);
        }
        __syncthreads();
    }

    // att weights for this wave's 64-col span (single head: span never crosses 256)
    int cbase = colBase + waveCol;
    int head = cbase >> 8;
    int part = (cblk & 1) * 2 + (wave & 1);
    float as4[4], ad4[4];
    #pragma unroll
    for (int j = 0; j < 4; ++j) {
        int off = (cbase + j * 16 + m16) & 255;
        as4[j] = att_s[head * 256 + off];
        ad4[j] = att_d[head * 256 + off];
    }

    // fp8 stores (C/D layout: col=lane&15, row=quad*4+reg) + alpha partials
    #pragma unroll
    for (int i = 0; i < 4; ++i) {
        int r0 = rowBase + waveRow + i * 16 + quad * 4;
        #pragma unroll
        for (int r = 0; r < 4; ++r) {
            int row = r0 + r;
            float ps = 0.f, pd = 0.f;
            #pragma unroll
            for (int j = 0; j < 4; ++j) {
                float h = acc[i][j][r];
                ps += h * as4[j];
                pd += h * ad4[j];
                if (row < M)
                    C8[(size_t)row * HC + colBase + waveCol + j * 16 + m16] = f32_to_fp8(h);
            }
            #pragma unroll
            for (int off = 1; off < 16; off <<= 1) {
                ps += __shfl_xor(ps, off);
                pd += __shfl_xor(pd, off);
            }
            if (m16 == 0 && row < M) {
                aprt_s[((size_t)part * M + row) * 4 + head] = ps;
                aprt_d[((size_t)part * M + row) * 4 + head] = pd;
            }
        }
    }
}

// ---------------- alpha partial reduce: asrc/adst[n] = sum over 4 parts ----------------

__global__ void alpha_sum_kernel(const float* __restrict__ aprt_s,
                                 const float* __restrict__ aprt_d,
                                 float* __restrict__ asrc, float* __restrict__ adst) {
    int n = blockIdx.x * 256 + threadIdx.x;
    if (n >= Nn) return;
    f32x4 s = {0.f, 0.f, 0.f, 0.f}, d = {0.f, 0.f, 0.f, 0.f};
    #pragma unroll
    for (int p = 0; p < 4; ++p) {
        f32x4 vs = ((const f32x4*)aprt_s)[(size_t)p * Nn + n];
        f32x4 vd = ((const f32x4*)aprt_d)[(size_t)p * Nn + n];
        #pragma unroll
        for (int k = 0; k < 4; ++k) { s[k] += vs[k]; d[k] += vd[k]; }
    }
    ((f32x4*)asrc)[n] = s;
    ((f32x4*)adst)[n] = d;
}

// ---------------- edge-weight precompute -> fused (src, ew) int2 streams ----------------
// r19: 16 lanes/node (avg degree 17 -> ~70% lane util, ~10000 wave-bodies).
// r22: writes ceT[head][e] = {src, bitcast(ew)} (int2, head-major) so agg stages
// ONE coalesced 8B load per edge instead of two 4B loads from separate arrays.
// Same values bit-identical; ew write traffic 16->32B/edge (~+1us/layer).

__global__ __launch_bounds__(256) void ew_kernel(const float* __restrict__ asrc,
                                                 const float* __restrict__ adst,
                                                 const int* __restrict__ row_ptr,
                                                 const int* __restrict__ csr_src,
                                                 int2* __restrict__ ceT,
                                                 float* __restrict__ dinv) {
    int grp = threadIdx.x >> 4, lane16 = threadIdx.x & 15;
    int n = blockIdx.x * 16 + grp;
    if (n >= Nn) return;
    int start = row_ptr[n], end = row_ptr[n + 1];
    f32x4 ad = ((const f32x4*)adst)[n];
    f32x4 d = {0.f, 0.f, 0.f, 0.f};
    for (int e = start + lane16; e < end; e += 16) {
        int s = csr_src[e];
        f32x4 as = ((const f32x4*)asrc)[s];
        #pragma unroll
        for (int k = 0; k < 4; ++k) {
            float z = as[k] + ad[k];
            z = (z > 0.f) ? z : NEG_SLOPE * z;
            float ex = __expf(z);
            int2 ce; ce.x = s; ce.y = __float_as_int(ex);
            ceT[(size_t)k * ETOT + e] = ce;
            d[k] += ex;
        }
    }
    #pragma unroll
    for (int off = 8; off > 0; off >>= 1) {
        #pragma unroll
        for (int k = 0; k < 4; ++k) d[k] += __shfl_xor(d[k], off);
    }
    if (lane16 == 0) {
        f32x4 iv;
        #pragma unroll
        for (int k = 0; k < 4; ++k) iv[k] = 1.f / (d[k] + 1e-16f);
        ((f32x4*)dinv)[n] = iv;
    }
}

// ---------------- sliced aggregation (r19 structure restored — empirical best) ----------
// r21 post-mortem: parity sub-group split REGRESSED (-3%) => straggler depth is
// NOT the limiter (falsified alongside ILP r18, LDS-atomics r20). This 32-slot x
// 8-ch-thread 16B-gather form is the measured floor across 5 structural variants.
// r22 delta: stage loop reads the fused ceT int2 stream (1 load/edge, not 2).
// grid (8, 625): slice -> XCD affinity; per-XCD footprint 2.5MB (96% L2 hit, r10).

__global__ __launch_bounds__(256) void agg_slice_kernel(
    const unsigned char* __restrict__ h8,
    const int2* __restrict__ ceT,
    const float* __restrict__ dinv,
    const int* __restrict__ row_ptr,
    const float* __restrict__ bias_l,
    __bf16* __restrict__ outb)
{
    int slice = blockIdx.x;              // 0..7
    int head = slice >> 1;
    int tid = threadIdx.x;
    int nslot = tid >> 3;                // 0..31
    int ch = tid & 7;                    // 16B fp8 group within 128B slice
    int n = blockIdx.y * 32 + nslot;

    __shared__ int2 ce_sh[1024];         // (src, bitcast ew)
    __shared__ int  rp_sh[33];

    if (tid < 33) rp_sh[tid] = row_ptr[blockIdx.y * 32 + tid];
    __syncthreads();
    int blk_lo = rp_sh[0], blk_hi = rp_sh[32];
    int start = rp_sh[nslot], end = rp_sh[nslot + 1];

    const unsigned char* hs = h8 + slice * 128 + ch * 16;
    const int2* ceh = ceT + (size_t)head * ETOT;
    float acc[16] = {};

    for (int c0 = blk_lo; c0 < blk_hi; c0 += 1024) {
        int c1 = min(c0 + 1024, blk_hi);
        int cnt = c1 - c0;
        for (int i = tid; i < cnt; i += 256)       // coalesced stage: one 8B load
            ce_sh[i] = ceh[c0 + i];
        __syncthreads();
        int lo = max(start, c0), hi = min(end, c1);
        for (int e = lo; e < hi; ++e) {
            int2 v = ce_sh[e - c0];
            float w = __int_as_float(v.y);
            uint4 u = *(const uint4*)(hs + (size_t)v.x * HC);
            f32x4 a0 = fp8x4_to_f32(u.x), a1 = fp8x4_to_f32(u.y);
            f32x4 a2 = fp8x4_to_f32(u.z), a3 = fp8x4_to_f32(u.w);
            #pragma unroll
            for (int k = 0; k < 4; ++k) {
                acc[k]      += w * a0[k];
                acc[k + 4]  += w * a1[k];
                acc[k + 8]  += w * a2[k];
                acc[k + 12] += w * a3[k];
            }
        }
        __syncthreads();
    }

    float inv = dinv[n * 4 + head];
    bf16x8 o0, o1;
    #pragma unroll
    for (int k = 0; k < 8; ++k) {
        o0[k] = (__bf16)fmaxf(acc[k] * inv + bias_l[slice * 128 + ch * 16 + k], 0.f);
        o1[k] = (__bf16)fmaxf(acc[k + 8] * inv + bias_l[slice * 128 + ch * 16 + 8 + k], 0.f);
    }
    *(bf16x8*)(outb + (size_t)n * HC + slice * 128 + ch * 16) = o0;
    *(bf16x8*)(outb + (size_t)n * HC + slice * 128 + ch * 16 + 8) = o1;
}

// ---------------- global mean pool (race-free partials) ----------------

__device__ __forceinline__ int lower_bound_batch(const int* __restrict__ batch, int val) {
    int lo = 0, hi = Nn;
    while (lo < hi) { int mid = (lo + hi) >> 1; if (batch[mid] < val) lo = mid + 1; else hi = mid; }
    return lo;
}

__global__ void pool_kernel(const __bf16* __restrict__ h2b, const int* __restrict__ batch,
                            float* __restrict__ pooledP) {
    int b = blockIdx.x, part = blockIdx.y;   // grid (B, 8)
    int tid = threadIdx.x;
    int start = lower_bound_batch(batch, b);
    int end   = lower_bound_batch(batch, b + 1);
    int len = end - start;
    int chunk = (len + 7) / 8;
    int s0 = start + part * chunk;
    int s1 = min(s0 + chunk, end);
    float acc[4] = {0.f, 0.f, 0.f, 0.f};
    for (int n = s0; n < s1; ++n) {
        bf16x4 v = ((const bf16x4*)(h2b + (size_t)n * HC))[tid];
        #pragma unroll
        for (int k = 0; k < 4; ++k) acc[k] += (float)v[k];
    }
    #pragma unroll
    for (int k = 0; k < 4; ++k)
        pooledP[((size_t)part * Bb + b) * HC + tid * 4 + k] = acc[k];
}

// ---------------- projection (k-split, race-free partials) + layernorm ----------------

__global__ __launch_bounds__(512) void proj_partial_kernel(const float* __restrict__ pooledP,
                                                           const int* __restrict__ batch,
                                                           const float* __restrict__ projW,
                                                           float* __restrict__ projP) {
    int b = blockIdx.x, part = blockIdx.y;   // grid (16, 8)
    int d = threadIdx.x;                     // 512
    __shared__ float psum[HC];
    int start = lower_bound_batch(batch, b);
    int end   = lower_bound_batch(batch, b + 1);
    float inv = 1.0f / fmaxf((float)(end - start), 1.0f);
    for (int k = d; k < HC; k += 512) {
        float s = 0.f;
        #pragma unroll
        for (int p = 0; p < 8; ++p) s += pooledP[((size_t)p * Bb + b) * HC + k];
        psum[k] = s * inv;
    }
    __syncthreads();
    float acc = 0.f;
    int k0 = part * 128;
    for (int k = k0; k < k0 + 128; ++k)
        acc += psum[k] * projW[(size_t)k * Dd + d];
    projP[((size_t)part * Bb + b) * Dd + d] = acc;
}

__global__ __launch_bounds__(512) void ln_kernel(const float* __restrict__ projP,
                                                 const float* __restrict__ projb,
                                                 const float* __restrict__ gamma,
                                                 const float* __restrict__ beta,
                                                 float* __restrict__ out) {
    int b = blockIdx.x;
    int d = threadIdx.x;
    __shared__ float red[512];
    float o = projb[d];
    #pragma unroll
    for (int p = 0; p < 8; ++p) o += projP[((size_t)p * Bb + b) * Dd + d];
    red[d] = o;
    __syncthreads();
    for (int off = 256; off > 0; off >>= 1) {
        if (d < off) red[d] += red[d + off];
        __syncthreads();
    }
    float mu = red[0] / (float)Dd;
    __syncthreads();
    float df = o - mu;
    red[d] = df * df;
    __syncthreads();
    for (int off = 256; off > 0; off >>= 1) {
        if (d < off) red[d] += red[d + off];
        __syncthreads();
    }
    float var = red[0] / (float)Dd;
    out[b * Dd + d] = df / sqrtf(var + LN_EPS) * gamma[d] + beta[d];
}

// ---------------- launch ----------------

extern "C" void kernel_launch(void* const* d_in, const int* in_sizes, int n_in,
                              void* d_out, int out_size, void* d_ws, size_t ws_size,
                              hipStream_t stream) {
    const float* x         = (const float*)d_in[0];
    const int*   ei        = (const int*)d_in[1];
    const int*   batch     = (const int*)d_in[2];
    const float* W0        = (const float*)d_in[3];
    const float* W_rest    = (const float*)d_in[4];
    const float* att_src   = (const float*)d_in[5];
    const float* att_dst   = (const float*)d_in[6];
    const float* conv_bias = (const float*)d_in[7];
    const float* proj_W    = (const float*)d_in[8];
    const float* proj_b    = (const float*)d_in[9];
    const float* ln_gamma  = (const float*)d_in[10];
    const float* ln_beta   = (const float*)d_in[11];
    float* out = (float*)d_out;

    char* ws = (char*)d_ws;
    size_t off = 0;
    auto alloc = [&](size_t bytes) {
        void* p = ws + off;
        off = (off + bytes + 255) & ~(size_t)255;
        return p;
    };
    unsigned char* h8 = (unsigned char*)alloc((size_t)Nn * HC);   // GEMM out (fp8, agg payload)
    __bf16* h2b     = (__bf16*)alloc((size_t)Nn * HC * 2);        // layer out (bf16)
    __bf16* xb      = (__bf16*)alloc((size_t)Nn * Dd * 2);
    __bf16* W0T     = (__bf16*)alloc((size_t)HC * Dd * 2);
    __bf16* WrT     = (__bf16*)alloc((size_t)3 * HC * HC * 2);
    float*  aprt_s  = (float*)alloc((size_t)4 * Nn * Hh * 4);     // alpha partials
    float*  aprt_d  = (float*)alloc((size_t)4 * Nn * Hh * 4);
    float*  asrc    = (float*)alloc((size_t)Nn * Hh * 4);
    float*  adst    = (float*)alloc((size_t)Nn * Hh * 4);
    int2*   ceT     = (int2*)alloc((size_t)Hh * ETOT * 8);        // fused (src, ew), head-major
    float*  dinv    = (float*)alloc((size_t)Nn * Hh * 4);
    int*    deg     = (int*)alloc((size_t)Nn * 4);
    int*    tmp     = (int*)alloc((size_t)Nn * 4);
    int*    bsum    = (int*)alloc((size_t)256 * 4);
    int*    row_ptr = (int*)alloc((size_t)(Nn + 1) * 4);
    int*    cursor  = (int*)alloc((size_t)Nn * 4);
    int*    csr_src = (int*)alloc((size_t)ETOT * 4);
    float*  pooledP = (float*)alloc((size_t)8 * Bb * HC * 4);
    float*  projP   = (float*)alloc((size_t)8 * Bb * Dd * 4);
    (void)ws_size; (void)in_sizes; (void)n_in; (void)out_size;

    // ---- build CSR by destination ----
    hipMemsetAsync(deg, 0, (size_t)Nn * 4, stream);
    count_deg_kernel<<<(ETOT + 255) / 256, 256, 0, stream>>>(ei, deg);
    scan1_kernel<<<NBLK, 256, 0, stream>>>(deg, tmp, bsum);
    scan2_kernel<<<1, 256, 0, stream>>>(bsum);
    scan3_kernel<<<NBLK, 256, 0, stream>>>(tmp, bsum, deg, row_ptr, cursor);
    scatter_kernel<<<(ETOT + 255) / 256, 256, 0, stream>>>(ei, cursor, csr_src);

    // ---- bf16 casts / weight transposes ----
    cast_kernel<<<(Nn * Dd / 4 + 255) / 256, 256, 0, stream>>>(x, xb, Nn * Dd / 4);
    transpose_cast_kernel<<<dim3(HC / 32, Dd / 32, 1), dim3(32, 8), 0, stream>>>(W0, W0T, Dd, HC);
    transpose_cast_kernel<<<dim3(HC / 32, HC / 32, 3), dim3(32, 8), 0, stream>>>(W_rest, WrT, HC, HC);

    // ---- GAT layers ----
    dim3 gemm_grid(8, 160);   // 1280 swizzled ids -> (157 row-blocks, 8 col-blocks)
    for (int l = 0; l < Ll; ++l) {
        const __bf16* Afeat = (l == 0) ? xb : h2b;
        int K = (l == 0) ? Dd : HC;
        const __bf16* BT = (l == 0) ? W0T : (WrT + (size_t)(l - 1) * HC * HC);
        mfma_gemm_kernel<<<gemm_grid, 256, 0, stream>>>(
            Afeat, BT, h8, att_src + l * HC, att_dst + l * HC, aprt_s, aprt_d, Nn, K);
        alpha_sum_kernel<<<NBLK, 256, 0, stream>>>(aprt_s, aprt_d, asrc, adst);
        ew_kernel<<<(Nn + 15) / 16, 256, 0, stream>>>(asrc, adst, row_ptr, csr_src, ceT, dinv);
        agg_slice_kernel<<<dim3(8, Nn / 32), 256, 0, stream>>>(
            h8, ceT, dinv, row_ptr, conv_bias + l * HC, h2b);
    }

    // ---- pool + proj + layernorm (all race-free partials, no memsets) ----
    pool_kernel<<<dim3(Bb, 8), 256, 0, stream>>>(h2b, batch, pooledP);
    proj_partial_kernel<<<dim3(Bb, 8), 512, 0, stream>>>(pooledP, batch, proj_W, projP);
    ln_kernel<<<Bb, 512, 0, stream>>>(projP, proj_b, ln_gamma, ln_beta, out);
}